// Round 8
// baseline (3035.506 us; speedup 1.0000x reference)
//
#include <hip/hip_runtime.h>
#include <stdint.h>

#define DET_THRESH 0.015f

// Hard-constraint FMA: acc pinned to arch-VGPR, weight in SGPR (wave-
// uniform s_load), activation in VGPR. Guarantees 1 VALU inst per MAC --
// the compiler's AGPR-parking of accumulators cost ~2-3 VALU/FMA (r3-r7:
// VGPR_Count 28-56 with 16-64 live accs, VALU time 1.9-2.9x FMA floor).
#define FMAC_S(accv, wv, av) \
  asm("v_fmac_f32 %0, %1, %2" : "+v"(accv) : "s"(wv), "v"(av))
#define FMAC_V(accv, wv, av) \
  asm("v_fmac_f32 %0, %1, %2" : "+v"(accv) : "v"(wv), "v"(av))

// =====================================================================
// Weight pre-transpose: w[co][ci][tap] -> wT[ci*9+tap][co]  (per layer)
// =====================================================================
struct TP {
  const float* src[8];
  float* dst[8];
  int cin[8];
  int cout[8];
};

__global__ __launch_bounds__(256) void k_wT(TP tp) {
  int l = blockIdx.y;
  int n = tp.cin[l] * tp.cout[l] * 9;
  int k = blockIdx.x * 256 + threadIdx.x;
  if (k >= n) return;
  int ci9 = tp.cin[l] * 9;
  int co = k / ci9;
  int r = k - co * ci9;             // r = ci*9 + tap
  tp.dst[l][(size_t)r * tp.cout[l] + co] = tp.src[l][k];
}

// =====================================================================
// Generic 3x3 conv (+bias+relu), optional fused 2x2 maxpool.
// Tile: 32 cols x 8 rows x 16 co. 256 thr: r=tid>>5 (0..7), c=tid&31.
// Thread: 1 row x 1 col x 16 co. Weights wave-uniform (s_load broadcast).
// =====================================================================
template <bool POOL>
__global__ __launch_bounds__(256) void k_conv(
    const float* __restrict__ in, const float* __restrict__ wT, const float* __restrict__ bias,
    float* __restrict__ out, int CIN, int COUT, int H, int W, int tilesX)
{
  __shared__ float ain[4][10][36];   // 4 ci x (8+2) rows x (32+2 pad->36) cols

  int tile = blockIdx.x;
  int tx = tile % tilesX, ty = tile / tilesX;
  int x0 = tx * 32, y0 = ty * 8;
  int cob = blockIdx.y * 16;
  int n = blockIdx.z;

  int tid = threadIdx.x;
  int r = tid >> 5;
  int c = tid & 31;

  float acc[16];
#pragma unroll
  for (int j = 0; j < 16; j++) acc[j] = 0.f;

  int nch = CIN >> 2;
  for (int cc = 0; cc < nch; ++cc) {
    __syncthreads();
    for (int m = tid; m < 1360; m += 256) {
      int ci = m / 340;
      int rem = m - ci * 340;
      int rr = rem / 34;
      int col = rem - rr * 34;
      int gy = y0 - 1 + rr, gx = x0 - 1 + col;
      float v = 0.f;
      if (gy >= 0 && gy < H && gx >= 0 && gx < W)
        v = in[(((size_t)n * CIN + (cc * 4 + ci)) * H + gy) * W + gx];
      ain[ci][rr][col] = v;
    }
    __syncthreads();
#pragma unroll
    for (int ci = 0; ci < 4; ++ci) {
      float win[3][3];
#pragma unroll
      for (int dy = 0; dy < 3; dy++) {
        win[dy][0] = ain[ci][r + dy][c];
        win[dy][1] = ain[ci][r + dy][c + 1];
        win[dy][2] = ain[ci][r + dy][c + 2];
      }
      const float* wp = wT + (size_t)((cc * 4 + ci) * 9) * COUT + cob;
#pragma unroll
      for (int tap = 0; tap < 9; tap++) {
        float4 q0 = *(const float4*)(wp + tap * COUT);
        float4 q1 = *(const float4*)(wp + tap * COUT + 4);
        float4 q2 = *(const float4*)(wp + tap * COUT + 8);
        float4 q3 = *(const float4*)(wp + tap * COUT + 12);
        float a = win[tap / 3][tap % 3];
        FMAC_S(acc[0],  q0.x, a);
        FMAC_S(acc[1],  q0.y, a);
        FMAC_S(acc[2],  q0.z, a);
        FMAC_S(acc[3],  q0.w, a);
        FMAC_S(acc[4],  q1.x, a);
        FMAC_S(acc[5],  q1.y, a);
        FMAC_S(acc[6],  q1.z, a);
        FMAC_S(acc[7],  q1.w, a);
        FMAC_S(acc[8],  q2.x, a);
        FMAC_S(acc[9],  q2.y, a);
        FMAC_S(acc[10], q2.z, a);
        FMAC_S(acc[11], q2.w, a);
        FMAC_S(acc[12], q3.x, a);
        FMAC_S(acc[13], q3.y, a);
        FMAC_S(acc[14], q3.z, a);
        FMAC_S(acc[15], q3.w, a);
      }
    }
  }

  float bvv[16];
  {
    const float4* bp = (const float4*)(bias + cob);
    *(float4*)&bvv[0] = bp[0]; *(float4*)&bvv[4] = bp[1];
    *(float4*)&bvv[8] = bp[2]; *(float4*)&bvv[12] = bp[3];
  }
  int x = x0 + c;
  int y = y0 + r;
  if (!POOL) {
    if (y < H && x < W) {
#pragma unroll
      for (int j = 0; j < 16; j++)
        out[(((size_t)n * COUT + cob + j) * H + y) * W + x] = fmaxf(acc[j] + bvv[j], 0.f);
    }
  } else {
    int Hp = H >> 1, Wp = W >> 1;
    int py = y >> 1, pxp = x >> 1;
    bool ok = ((r & 1) == 0) && ((c & 1) == 0) && (py < Hp) && (pxp < Wp);
#pragma unroll
    for (int j = 0; j < 16; j++) {
      float h = fmaxf(acc[j] + bvv[j], 0.f);
      float hc = fmaxf(h, __shfl_xor(h, 1, 64));    // col pair
      float hv = fmaxf(hc, __shfl_xor(hc, 32, 64)); // row pair
      if (ok)
        out[(((size_t)n * COUT + cob + j) * Hp + py) * Wp + pxp] = hv;
    }
  }
}

// =====================================================================
// Fused conv0(1->64)+relu -> conv1(64->64)+relu -> 2x2 maxpool.
// =====================================================================
__global__ __launch_bounds__(256) void k_f01(
    const float* __restrict__ x, const float* __restrict__ w0g, const float* __restrict__ b0g,
    const float* __restrict__ wT1, const float* __restrict__ b1g, float* __restrict__ out)
{
  const int H = 240, W = 320;
  __shared__ float in_raw[12][36];
  __shared__ float a0[4][10][36];
  __shared__ float w0l[576];
  __shared__ float b0l[64];

  int tile = blockIdx.x;              // tilesX=10, tilesY=30
  int tx = tile % 10, ty = tile / 10;
  int x0 = tx * 32, y0 = ty * 8;
  int cob = blockIdx.y * 16;          // 0..3
  int n = blockIdx.z;

  int tid = threadIdx.x;
  int r = tid >> 5;
  int c = tid & 31;

  for (int k = tid; k < 576; k += 256) w0l[k] = w0g[k];
  if (tid < 64) b0l[tid] = b0g[tid];
  for (int m = tid; m < 432; m += 256) {
    int rr = m / 36, col = m - rr * 36;
    int gy = y0 - 2 + rr, gx = x0 - 2 + col;
    in_raw[rr][col] = (gy >= 0 && gy < H && gx >= 0 && gx < W)
                          ? x[(size_t)n * (H * W) + gy * W + gx] : 0.f;
  }

  float acc[16];
#pragma unroll
  for (int j = 0; j < 16; j++) acc[j] = 0.f;

  for (int cc = 0; cc < 16; ++cc) {
    __syncthreads();                  // in_raw/w0l ready; a0 free
    // conv0 chunk -> a0 (zero OUTSIDE image: conv1 'SAME' zero-padding)
    for (int m = tid; m < 1360; m += 256) {
      int ch = m / 340;
      int rem = m - ch * 340;
      int rr = rem / 34;
      int col = rem - rr * 34;
      int gy = y0 - 1 + rr, gx = x0 - 1 + col;
      float v = 0.f;
      if (gy >= 0 && gy < H && gx >= 0 && gx < W) {
        const float* wp = &w0l[(cc * 4 + ch) * 9];
        float s = b0l[cc * 4 + ch];
#pragma unroll
        for (int dy = 0; dy < 3; dy++)
#pragma unroll
          for (int dx = 0; dx < 3; dx++)
            s = fmaf(in_raw[rr + dy][col + dx], wp[dy * 3 + dx], s);
        v = fmaxf(s, 0.f);
      }
      a0[ch][rr][col] = v;
    }
    __syncthreads();
#pragma unroll
    for (int ci = 0; ci < 4; ++ci) {
      float win[3][3];
#pragma unroll
      for (int dy = 0; dy < 3; dy++) {
        win[dy][0] = a0[ci][r + dy][c];
        win[dy][1] = a0[ci][r + dy][c + 1];
        win[dy][2] = a0[ci][r + dy][c + 2];
      }
      const float* wp = wT1 + (size_t)((cc * 4 + ci) * 9) * 64 + cob;
#pragma unroll
      for (int tap = 0; tap < 9; tap++) {
        float4 q0 = *(const float4*)(wp + tap * 64);
        float4 q1 = *(const float4*)(wp + tap * 64 + 4);
        float4 q2 = *(const float4*)(wp + tap * 64 + 8);
        float4 q3 = *(const float4*)(wp + tap * 64 + 12);
        float a = win[tap / 3][tap % 3];
        FMAC_S(acc[0],  q0.x, a);
        FMAC_S(acc[1],  q0.y, a);
        FMAC_S(acc[2],  q0.z, a);
        FMAC_S(acc[3],  q0.w, a);
        FMAC_S(acc[4],  q1.x, a);
        FMAC_S(acc[5],  q1.y, a);
        FMAC_S(acc[6],  q1.z, a);
        FMAC_S(acc[7],  q1.w, a);
        FMAC_S(acc[8],  q2.x, a);
        FMAC_S(acc[9],  q2.y, a);
        FMAC_S(acc[10], q2.z, a);
        FMAC_S(acc[11], q2.w, a);
        FMAC_S(acc[12], q3.x, a);
        FMAC_S(acc[13], q3.y, a);
        FMAC_S(acc[14], q3.z, a);
        FMAC_S(acc[15], q3.w, a);
      }
    }
  }

  // bias + relu + 2x2 maxpool + store (out: 8,64,120,160)
  float bvv[16];
  {
    const float4* bp = (const float4*)(b1g + cob);
    *(float4*)&bvv[0] = bp[0]; *(float4*)&bvv[4] = bp[1];
    *(float4*)&bvv[8] = bp[2]; *(float4*)&bvv[12] = bp[3];
  }
  int Hp = 120, Wp = 160;
  int py = (y0 + r) >> 1, pxp = (x0 + c) >> 1;
  bool ok = ((r & 1) == 0) && ((c & 1) == 0);
#pragma unroll
  for (int j = 0; j < 16; j++) {
    float h = fmaxf(acc[j] + bvv[j], 0.f);
    float hc = fmaxf(h, __shfl_xor(h, 1, 64));
    float hv = fmaxf(hc, __shfl_xor(hc, 32, 64));
    if (ok)
      out[(((size_t)n * 64 + cob + j) * Hp + py) * Wp + pxp] = hv;
  }
}

// =====================================================================
// Head: conv9 (1x1, 256->65) + bias + softmax(65) + drop dustbin + shuffle
// 2-lane teams: even lane co 0..33, odd lane co 34..64.
// =====================================================================
__global__ __launch_bounds__(256) void k_head(
    const float* __restrict__ act, const float* __restrict__ w9, const float* __restrict__ b9,
    float* __restrict__ prob)
{
  __shared__ float wl[256 * 68];
  int n = blockIdx.y;
  int tid = threadIdx.x;
  for (int k = tid; k < 65 * 256; k += 256) {
    int co = k / 256, ci = k % 256;
    wl[ci * 68 + co] = w9[k];
  }
  for (int ci = tid; ci < 256; ci += 256) {
    wl[ci * 68 + 65] = 0.f; wl[ci * 68 + 66] = 0.f; wl[ci * 68 + 67] = 0.f;
  }
  __syncthreads();
  int px = blockIdx.x * 128 + (tid >> 1);
  int half = tid & 1;
  bool live = (px < 1200);
  int cbase = half * 34;
  int nreal = half ? 31 : 34;    // real co count (incl. dustbin 64 on odd)

  float accv[34];
#pragma unroll
  for (int i = 0; i < 34; i++) accv[i] = 0.f;

  if (live) {
    for (int ci = 0; ci < 256; ++ci) {
      float a = act[((size_t)n * 256 + ci) * 1200 + px];
      const float2* wp = (const float2*)&wl[ci * 68 + cbase];
#pragma unroll
      for (int g = 0; g < 17; g++) {
        float2 wv = wp[g];
        FMAC_V(accv[g * 2 + 0], wv.x, a);
        FMAC_V(accv[g * 2 + 1], wv.y, a);
      }
    }
  }
  // bias + softmax across the lane pair
  for (int i = 0; i < 34; i++)
    if (i < nreal) accv[i] += b9[cbase + i];
  float m = -1e30f;
  for (int i = 0; i < 34; i++)
    if (i < nreal) m = fmaxf(m, accv[i]);
  m = fmaxf(m, __shfl_xor(m, 1, 64));
  float s = 0.f;
  for (int i = 0; i < 34; i++)
    if (i < nreal) { accv[i] = __expf(accv[i] - m); s += accv[i]; }
  s += __shfl_xor(s, 1, 64);
  float inv = 1.f / s;

  if (live) {
    int hc = px / 40, wc = px % 40;
    float* pb = prob + (size_t)n * 76800;
    int nw = half ? 30 : 34;     // write only co < 64
    for (int i = 0; i < nw; i++) {
      int co = cbase + i;
      pb[(hc * 8 + (co >> 3)) * 320 + wc * 8 + (co & 7)] = accv[i] * inv;
    }
  }
}

// =====================================================================
// Exact reference NMS per image.
// =====================================================================
#define MAXC 1024
__global__ __launch_bounds__(1024) void k_nms(
    const float* __restrict__ prob, float* __restrict__ onms, float* __restrict__ opred)
{
  __shared__ unsigned sup[MAXC * 32];
  __shared__ unsigned long long skey[MAXC];
  __shared__ unsigned syx[MAXC];
  __shared__ unsigned hist[256];
  __shared__ unsigned vword[32];
  __shared__ unsigned sh_prefix, sh_K, sh_cG, sh_pG, sh_pE;

  int n = blockIdx.x;
  int tid = threadIdx.x;
  const float* p = prob + (size_t)n * 76800;
  float* on = onms + (size_t)n * 76800;
  float* op = opred + (size_t)n * 76800;

  for (int k = tid; k < 76800; k += 1024) { on[k] = 0.f; op[k] = 0.f; }

  if (tid == 0) { sh_prefix = 0u; sh_K = MAXC; sh_cG = 0u; sh_pG = 0u; sh_pE = 0u; }

  for (int round = 0; round < 4; ++round) {
    if (tid < 256) hist[tid] = 0u;
    __syncthreads();
    unsigned prefix = sh_prefix;
    int shift = 24 - 8 * round;
    unsigned maskHi = (round == 0) ? 0u : (0xFFFFFFFFu << (shift + 8));
    for (int k = tid; k < 76800; k += 1024) {
      unsigned b = __float_as_uint(p[k]);
      if ((b & maskHi) == prefix) atomicAdd(&hist[(b >> shift) & 255], 1u);
    }
    __syncthreads();
    if (tid == 0) {
      unsigned K = sh_K, cum = 0u;
      int bin = 255;
      for (; bin >= 0; --bin) {
        unsigned cgt = hist[bin];
        if (cum + cgt >= K) break;
        cum += cgt;
      }
      sh_prefix = prefix | ((unsigned)bin << shift);
      sh_K = K - cum;
      sh_cG += cum;
    }
    __syncthreads();
  }
  unsigned T = sh_prefix;
  unsigned Kfill = sh_K;
  unsigned Cgt = sh_cG;

  unsigned* eq = sup;
  __syncthreads();
  for (int k = tid; k < 76800; k += 1024) {
    unsigned b = __float_as_uint(p[k]);
    if (b > T) {
      unsigned pos = atomicAdd(&sh_pG, 1u);
      skey[pos] = ((unsigned long long)b << 32) | (unsigned)(~(unsigned)k);
    } else if (b == T) {
      unsigned pos = atomicAdd(&sh_pE, 1u);
      if (pos < 2048u) eq[pos] = (unsigned)k;
    }
  }
  __syncthreads();
  unsigned cE = sh_pE;
  for (int k = tid; k < 2048; k += 1024)
    if ((unsigned)k >= cE) eq[k] = 0xFFFFFFFFu;
  __syncthreads();
  for (int k = 2; k <= 2048; k <<= 1) {
    for (int j = k >> 1; j > 0; j >>= 1) {
      int t = tid;
      int i = ((t & ~(j - 1)) << 1) | (t & (j - 1));
      int l = i | j;
      bool up = ((i & k) == 0);
      unsigned a = eq[i], b2 = eq[l];
      if (up ? (a > b2) : (a < b2)) { eq[i] = b2; eq[l] = a; }
      __syncthreads();
    }
  }
  for (int m2 = tid; m2 < (int)Kfill; m2 += 1024)
    skey[Cgt + m2] = ((unsigned long long)T << 32) | (unsigned)(~eq[m2]);
  __syncthreads();

  for (int k = 2; k <= MAXC; k <<= 1) {
    for (int j = k >> 1; j > 0; j >>= 1) {
      int i = tid;
      int l = i ^ j;
      if (l > i) {
        unsigned long long a = skey[i], b2 = skey[l];
        bool up = ((i & k) == 0);
        if (up ? (a < b2) : (a > b2)) { skey[i] = b2; skey[l] = a; }
      }
      __syncthreads();
    }
  }

  if (tid < 32) vword[tid] = 0u;
  __syncthreads();
  {
    unsigned long long key = skey[tid];
    unsigned vb = (unsigned)(key >> 32);
    float val = __uint_as_float(vb);
    unsigned id = ~(unsigned)key;
    unsigned y = id / 320u, xx = id - 320u * y;
    syx[tid] = (y << 16) | xx;
    if (val > DET_THRESH) atomicOr(&vword[tid >> 5], 1u << (tid & 31));
  }
  __syncthreads();

  {
    unsigned myyx = syx[tid];
    int ty = (int)(myyx >> 16), tx = (int)(myyx & 0xFFFFu);
    for (int w = 0; w < 32; ++w) {
      unsigned bits = 0u;
#pragma unroll 8
      for (int b2 = 0; b2 < 32; ++b2) {
        int j = w * 32 + b2;
        if (j > tid) {
          unsigned o = syx[j];
          int dy = ty - (int)(o >> 16); dy = dy < 0 ? -dy : dy;
          int dx = tx - (int)(o & 0xFFFFu); dx = dx < 0 ? -dx : dx;
          if (((dy | dx) < 4) && (dy + dx) <= 4) bits |= 1u << b2;
        }
      }
      sup[tid * 32 + w] = bits;
    }
  }
  __syncthreads();

  if (tid < 64) {
    int lw = tid;
    unsigned keepw = (lw < 32) ? vword[lw] : 0u;
    for (int i = 0; i < MAXC; ++i) {
      unsigned kword = __shfl(keepw, i >> 5, 64);
      if ((kword >> (i & 31)) & 1u) {
        if (lw < 32) keepw &= ~sup[i * 32 + lw];
      }
    }
    unsigned pc = (lw < 32) ? (unsigned)__builtin_popcount(keepw) : 0u;
    unsigned incl = pc;
    for (int d = 1; d < 32; d <<= 1) {
      unsigned t2 = __shfl_up(incl, d, 64);
      if (lw >= d) incl += t2;
    }
    unsigned excl = incl - pc;
    if (lw < 32) {
      int quota = 300 - (int)excl;
      if (quota <= 0) keepw = 0u;
      else if ((int)pc > quota) {
        while (__builtin_popcount(keepw) > quota)
          keepw &= ~(1u << (31 - __builtin_clz(keepw)));
      }
      unsigned kw = keepw;
      while (kw) {
        int b2 = __builtin_ffs((int)kw) - 1;
        kw &= kw - 1u;
        int i = lw * 32 + b2;
        unsigned long long key = skey[i];
        float v = __uint_as_float((unsigned)(key >> 32));
        unsigned id = ~(unsigned)key;
        on[id] = v;
        op[id] = v;
      }
    }
  }
}

// =====================================================================
extern "C" void kernel_launch(void* const* d_in, const int* in_sizes, int n_in,
                              void* d_out, int out_size, void* d_ws, size_t ws_size,
                              hipStream_t stream) {
  const float* x = (const float*)d_in[0];
  const float* w[10];
  const float* b[10];
  for (int i = 0; i < 10; ++i) {
    w[i] = (const float*)d_in[1 + 2 * i];
    b[i] = (const float*)d_in[2 + 2 * i];
  }
  float* A = (float*)d_ws;
  float* B = A + 9830400;        // 64*120*160*8
  float* prob  = (float*)d_out;
  float* onms  = prob + 614400;  // 8*240*320
  float* opred = onms + 614400;

  // Transposed weights live in the onms/opred region (dead until k_nms,
  // which rewrites it entirely). Total 921600 floats <= 1228800 available.
  float* wT1 = onms;
  float* wT2 = wT1 + 36864;
  float* wT3 = wT2 + 36864;
  float* wT4 = wT3 + 36864;
  float* wT5 = wT4 + 73728;
  float* wT6 = wT5 + 147456;
  float* wT7 = wT6 + 147456;
  float* wT8 = wT7 + 147456;

  TP tp;
  tp.src[0] = w[1]; tp.dst[0] = wT1; tp.cin[0] = 64;  tp.cout[0] = 64;
  tp.src[1] = w[2]; tp.dst[1] = wT2; tp.cin[1] = 64;  tp.cout[1] = 64;
  tp.src[2] = w[3]; tp.dst[2] = wT3; tp.cin[2] = 64;  tp.cout[2] = 64;
  tp.src[3] = w[4]; tp.dst[3] = wT4; tp.cin[3] = 64;  tp.cout[3] = 128;
  tp.src[4] = w[5]; tp.dst[4] = wT5; tp.cin[4] = 128; tp.cout[4] = 128;
  tp.src[5] = w[6]; tp.dst[5] = wT6; tp.cin[5] = 128; tp.cout[5] = 128;
  tp.src[6] = w[7]; tp.dst[6] = wT7; tp.cin[6] = 128; tp.cout[6] = 128;
  tp.src[7] = w[8]; tp.dst[7] = wT8; tp.cin[7] = 128; tp.cout[7] = 256;
  k_wT<<<dim3(1152, 8), 256, 0, stream>>>(tp);

  // conv0+conv1+pool -> A (8,64,120,160). tiles 10x30.
  k_f01<<<dim3(300, 4, 8), 256, 0, stream>>>(x, w[0], b[0], wT1, b[1], A);
  // conv2 -> B (8,64,120,160). tiles 5x15.
  k_conv<false><<<dim3(75, 4, 8), 256, 0, stream>>>(A, wT2, b[2], B, 64, 64, 120, 160, 5);
  // conv3+pool -> A (8,64,60,80)
  k_conv<true ><<<dim3(75, 4, 8), 256, 0, stream>>>(B, wT3, b[3], A, 64, 64, 120, 160, 5);
  // conv4 -> B (8,128,60,80). tiles 3x8.
  k_conv<false><<<dim3(24, 8, 8), 256, 0, stream>>>(A, wT4, b[4], B, 64, 128, 60, 80, 3);
  // conv5+pool -> A (8,128,30,40)
  k_conv<true ><<<dim3(24, 8, 8), 256, 0, stream>>>(B, wT5, b[5], A, 128, 128, 60, 80, 3);
  // conv6 -> B (8,128,30,40). tiles 2x4.
  k_conv<false><<<dim3(8, 8, 8), 256, 0, stream>>>(A, wT6, b[6], B, 128, 128, 30, 40, 2);
  // conv7 -> A
  k_conv<false><<<dim3(8, 8, 8), 256, 0, stream>>>(B, wT7, b[7], A, 128, 128, 30, 40, 2);
  // conv8 -> B (8,256,30,40)
  k_conv<false><<<dim3(8, 16, 8), 256, 0, stream>>>(A, wT8, b[8], B, 128, 256, 30, 40, 2);
  // convPb + softmax + shuffle -> prob. 10 blocks x 128 px.
  k_head<<<dim3(10, 8), 256, 0, stream>>>(B, w[9], b[9], prob);
  // NMS + top-300 -> prob_nms, pred (rewrites the wT region)
  k_nms<<<dim3(8), 1024, 0, stream>>>(prob, onms, opred);
}

// Round 9
// 2692.484 us; speedup vs baseline: 1.1274x; 1.1274x over previous
//
#include <hip/hip_runtime.h>
#include <stdint.h>

#define DET_THRESH 0.015f

// Clamp occupancy target to 4 waves/EU: per-wave arch-VGPR budget = 128,
// comfortably above the ~45 live values in the conv kernels, so the
// allocator keeps accumulators in VGPRs instead of AGPR round-trips.
// (r6 tried (2,2) with a 110-value kernel -> still parked; r7 shrank the
// kernel but left target at max-occupancy -> VGPR_Count 28 + AGPR traffic,
// measured ~1.9 VALU slots per FMA. This combines both fixes.)
#define OCC4 __attribute__((amdgpu_waves_per_eu(4, 4)))

// =====================================================================
// Weight pre-transpose: w[co][ci][tap] -> wT[ci*9+tap][co]  (per layer)
// =====================================================================
struct TP {
  const float* src[8];
  float* dst[8];
  int cin[8];
  int cout[8];
};

__global__ __launch_bounds__(256) void k_wT(TP tp) {
  int l = blockIdx.y;
  int n = tp.cin[l] * tp.cout[l] * 9;
  int k = blockIdx.x * 256 + threadIdx.x;
  if (k >= n) return;
  int ci9 = tp.cin[l] * 9;
  int co = k / ci9;
  int r = k - co * ci9;             // r = ci*9 + tap
  tp.dst[l][(size_t)r * tp.cout[l] + co] = tp.src[l][k];
}

// =====================================================================
// Generic 3x3 conv (+bias+relu), optional fused 2x2 maxpool.
// Tile: 32 cols x 8 rows x 16 co. 256 thr: r=tid>>5 (0..7), c=tid&31.
// Thread: 1 row x 1 col x 16 co. Weights wave-uniform (s_load broadcast).
// =====================================================================
template <bool POOL>
__global__ __launch_bounds__(256) OCC4 void k_conv(
    const float* __restrict__ in, const float* __restrict__ wT, const float* __restrict__ bias,
    float* __restrict__ out, int CIN, int COUT, int H, int W, int tilesX)
{
  __shared__ float ain[4][10][36];   // 4 ci x (8+2) rows x (32+2 pad->36) cols

  int tile = blockIdx.x;
  int tx = tile % tilesX, ty = tile / tilesX;
  int x0 = tx * 32, y0 = ty * 8;
  int cob = blockIdx.y * 16;
  int n = blockIdx.z;

  int tid = threadIdx.x;
  int r = tid >> 5;
  int c = tid & 31;

  float acc[16];
#pragma unroll
  for (int j = 0; j < 16; j++) acc[j] = 0.f;

  int nch = CIN >> 2;
  for (int cc = 0; cc < nch; ++cc) {
    __syncthreads();
    for (int m = tid; m < 1360; m += 256) {
      int ci = m / 340;
      int rem = m - ci * 340;
      int rr = rem / 34;
      int col = rem - rr * 34;
      int gy = y0 - 1 + rr, gx = x0 - 1 + col;
      float v = 0.f;
      if (gy >= 0 && gy < H && gx >= 0 && gx < W)
        v = in[(((size_t)n * CIN + (cc * 4 + ci)) * H + gy) * W + gx];
      ain[ci][rr][col] = v;
    }
    __syncthreads();
#pragma unroll
    for (int ci = 0; ci < 4; ++ci) {
      float win[3][3];
#pragma unroll
      for (int dy = 0; dy < 3; dy++) {
        win[dy][0] = ain[ci][r + dy][c];
        win[dy][1] = ain[ci][r + dy][c + 1];
        win[dy][2] = ain[ci][r + dy][c + 2];
      }
      const float* wp = wT + (size_t)((cc * 4 + ci) * 9) * COUT + cob;
#pragma unroll
      for (int tap = 0; tap < 9; tap++) {
        float4 q0 = *(const float4*)(wp + tap * COUT);
        float4 q1 = *(const float4*)(wp + tap * COUT + 4);
        float4 q2 = *(const float4*)(wp + tap * COUT + 8);
        float4 q3 = *(const float4*)(wp + tap * COUT + 12);
        float a = win[tap / 3][tap % 3];
        acc[0]  = fmaf(a, q0.x, acc[0]);
        acc[1]  = fmaf(a, q0.y, acc[1]);
        acc[2]  = fmaf(a, q0.z, acc[2]);
        acc[3]  = fmaf(a, q0.w, acc[3]);
        acc[4]  = fmaf(a, q1.x, acc[4]);
        acc[5]  = fmaf(a, q1.y, acc[5]);
        acc[6]  = fmaf(a, q1.z, acc[6]);
        acc[7]  = fmaf(a, q1.w, acc[7]);
        acc[8]  = fmaf(a, q2.x, acc[8]);
        acc[9]  = fmaf(a, q2.y, acc[9]);
        acc[10] = fmaf(a, q2.z, acc[10]);
        acc[11] = fmaf(a, q2.w, acc[11]);
        acc[12] = fmaf(a, q3.x, acc[12]);
        acc[13] = fmaf(a, q3.y, acc[13]);
        acc[14] = fmaf(a, q3.z, acc[14]);
        acc[15] = fmaf(a, q3.w, acc[15]);
      }
    }
  }

  float bvv[16];
  {
    const float4* bp = (const float4*)(bias + cob);
    *(float4*)&bvv[0] = bp[0]; *(float4*)&bvv[4] = bp[1];
    *(float4*)&bvv[8] = bp[2]; *(float4*)&bvv[12] = bp[3];
  }
  int x = x0 + c;
  int y = y0 + r;
  if (!POOL) {
    if (y < H && x < W) {
#pragma unroll
      for (int j = 0; j < 16; j++)
        out[(((size_t)n * COUT + cob + j) * H + y) * W + x] = fmaxf(acc[j] + bvv[j], 0.f);
    }
  } else {
    int Hp = H >> 1, Wp = W >> 1;
    int py = y >> 1, pxp = x >> 1;
    bool ok = ((r & 1) == 0) && ((c & 1) == 0) && (py < Hp) && (pxp < Wp);
#pragma unroll
    for (int j = 0; j < 16; j++) {
      float h = fmaxf(acc[j] + bvv[j], 0.f);
      float hc = fmaxf(h, __shfl_xor(h, 1, 64));    // col pair
      float hv = fmaxf(hc, __shfl_xor(hc, 32, 64)); // row pair
      if (ok)
        out[(((size_t)n * COUT + cob + j) * Hp + py) * Wp + pxp] = hv;
    }
  }
}

// =====================================================================
// Fused conv0(1->64)+relu -> conv1(64->64)+relu -> 2x2 maxpool.
// =====================================================================
__global__ __launch_bounds__(256) OCC4 void k_f01(
    const float* __restrict__ x, const float* __restrict__ w0g, const float* __restrict__ b0g,
    const float* __restrict__ wT1, const float* __restrict__ b1g, float* __restrict__ out)
{
  const int H = 240, W = 320;
  __shared__ float in_raw[12][36];
  __shared__ float a0[4][10][36];
  __shared__ float w0l[576];
  __shared__ float b0l[64];

  int tile = blockIdx.x;              // tilesX=10, tilesY=30
  int tx = tile % 10, ty = tile / 10;
  int x0 = tx * 32, y0 = ty * 8;
  int cob = blockIdx.y * 16;          // 0..3
  int n = blockIdx.z;

  int tid = threadIdx.x;
  int r = tid >> 5;
  int c = tid & 31;

  for (int k = tid; k < 576; k += 256) w0l[k] = w0g[k];
  if (tid < 64) b0l[tid] = b0g[tid];
  for (int m = tid; m < 432; m += 256) {
    int rr = m / 36, col = m - rr * 36;
    int gy = y0 - 2 + rr, gx = x0 - 2 + col;
    in_raw[rr][col] = (gy >= 0 && gy < H && gx >= 0 && gx < W)
                          ? x[(size_t)n * (H * W) + gy * W + gx] : 0.f;
  }

  float acc[16];
#pragma unroll
  for (int j = 0; j < 16; j++) acc[j] = 0.f;

  for (int cc = 0; cc < 16; ++cc) {
    __syncthreads();                  // in_raw/w0l ready; a0 free
    // conv0 chunk -> a0 (zero OUTSIDE image: conv1 'SAME' zero-padding)
    for (int m = tid; m < 1360; m += 256) {
      int ch = m / 340;
      int rem = m - ch * 340;
      int rr = rem / 34;
      int col = rem - rr * 34;
      int gy = y0 - 1 + rr, gx = x0 - 1 + col;
      float v = 0.f;
      if (gy >= 0 && gy < H && gx >= 0 && gx < W) {
        const float* wp = &w0l[(cc * 4 + ch) * 9];
        float s = b0l[cc * 4 + ch];
#pragma unroll
        for (int dy = 0; dy < 3; dy++)
#pragma unroll
          for (int dx = 0; dx < 3; dx++)
            s = fmaf(in_raw[rr + dy][col + dx], wp[dy * 3 + dx], s);
        v = fmaxf(s, 0.f);
      }
      a0[ch][rr][col] = v;
    }
    __syncthreads();
#pragma unroll
    for (int ci = 0; ci < 4; ++ci) {
      float win[3][3];
#pragma unroll
      for (int dy = 0; dy < 3; dy++) {
        win[dy][0] = a0[ci][r + dy][c];
        win[dy][1] = a0[ci][r + dy][c + 1];
        win[dy][2] = a0[ci][r + dy][c + 2];
      }
      const float* wp = wT1 + (size_t)((cc * 4 + ci) * 9) * 64 + cob;
#pragma unroll
      for (int tap = 0; tap < 9; tap++) {
        float4 q0 = *(const float4*)(wp + tap * 64);
        float4 q1 = *(const float4*)(wp + tap * 64 + 4);
        float4 q2 = *(const float4*)(wp + tap * 64 + 8);
        float4 q3 = *(const float4*)(wp + tap * 64 + 12);
        float a = win[tap / 3][tap % 3];
        acc[0]  = fmaf(a, q0.x, acc[0]);
        acc[1]  = fmaf(a, q0.y, acc[1]);
        acc[2]  = fmaf(a, q0.z, acc[2]);
        acc[3]  = fmaf(a, q0.w, acc[3]);
        acc[4]  = fmaf(a, q1.x, acc[4]);
        acc[5]  = fmaf(a, q1.y, acc[5]);
        acc[6]  = fmaf(a, q1.z, acc[6]);
        acc[7]  = fmaf(a, q1.w, acc[7]);
        acc[8]  = fmaf(a, q2.x, acc[8]);
        acc[9]  = fmaf(a, q2.y, acc[9]);
        acc[10] = fmaf(a, q2.z, acc[10]);
        acc[11] = fmaf(a, q2.w, acc[11]);
        acc[12] = fmaf(a, q3.x, acc[12]);
        acc[13] = fmaf(a, q3.y, acc[13]);
        acc[14] = fmaf(a, q3.z, acc[14]);
        acc[15] = fmaf(a, q3.w, acc[15]);
      }
    }
  }

  // bias + relu + 2x2 maxpool + store (out: 8,64,120,160)
  float bvv[16];
  {
    const float4* bp = (const float4*)(b1g + cob);
    *(float4*)&bvv[0] = bp[0]; *(float4*)&bvv[4] = bp[1];
    *(float4*)&bvv[8] = bp[2]; *(float4*)&bvv[12] = bp[3];
  }
  int Hp = 120, Wp = 160;
  int py = (y0 + r) >> 1, pxp = (x0 + c) >> 1;
  bool ok = ((r & 1) == 0) && ((c & 1) == 0);
#pragma unroll
  for (int j = 0; j < 16; j++) {
    float h = fmaxf(acc[j] + bvv[j], 0.f);
    float hc = fmaxf(h, __shfl_xor(h, 1, 64));
    float hv = fmaxf(hc, __shfl_xor(hc, 32, 64));
    if (ok)
      out[(((size_t)n * 64 + cob + j) * Hp + py) * Wp + pxp] = hv;
  }
}

// =====================================================================
// Head: conv9 (1x1, 256->65) + bias + softmax(65) + drop dustbin + shuffle
// 2-lane teams: even lane co 0..33, odd lane co 34..64.
// =====================================================================
__global__ __launch_bounds__(256) OCC4 void k_head(
    const float* __restrict__ act, const float* __restrict__ w9, const float* __restrict__ b9,
    float* __restrict__ prob)
{
  __shared__ float wl[256 * 68];
  int n = blockIdx.y;
  int tid = threadIdx.x;
  for (int k = tid; k < 65 * 256; k += 256) {
    int co = k / 256, ci = k % 256;
    wl[ci * 68 + co] = w9[k];
  }
  for (int ci = tid; ci < 256; ci += 256) {
    wl[ci * 68 + 65] = 0.f; wl[ci * 68 + 66] = 0.f; wl[ci * 68 + 67] = 0.f;
  }
  __syncthreads();
  int px = blockIdx.x * 128 + (tid >> 1);
  int half = tid & 1;
  bool live = (px < 1200);
  int cbase = half * 34;
  int nreal = half ? 31 : 34;    // real co count (incl. dustbin 64 on odd)

  float accv[34];
#pragma unroll
  for (int i = 0; i < 34; i++) accv[i] = 0.f;

  if (live) {
    for (int ci = 0; ci < 256; ++ci) {
      float a = act[((size_t)n * 256 + ci) * 1200 + px];
      const float2* wp = (const float2*)&wl[ci * 68 + cbase];
#pragma unroll
      for (int g = 0; g < 17; g++) {
        float2 wv = wp[g];
        accv[g * 2 + 0] = fmaf(a, wv.x, accv[g * 2 + 0]);
        accv[g * 2 + 1] = fmaf(a, wv.y, accv[g * 2 + 1]);
      }
    }
  }
  // bias + softmax across the lane pair
  for (int i = 0; i < 34; i++)
    if (i < nreal) accv[i] += b9[cbase + i];
  float m = -1e30f;
  for (int i = 0; i < 34; i++)
    if (i < nreal) m = fmaxf(m, accv[i]);
  m = fmaxf(m, __shfl_xor(m, 1, 64));
  float s = 0.f;
  for (int i = 0; i < 34; i++)
    if (i < nreal) { accv[i] = __expf(accv[i] - m); s += accv[i]; }
  s += __shfl_xor(s, 1, 64);
  float inv = 1.f / s;

  if (live) {
    int hc = px / 40, wc = px % 40;
    float* pb = prob + (size_t)n * 76800;
    int nw = half ? 30 : 34;     // write only co < 64
    for (int i = 0; i < nw; i++) {
      int co = cbase + i;
      pb[(hc * 8 + (co >> 3)) * 320 + wc * 8 + (co & 7)] = accv[i] * inv;
    }
  }
}

// =====================================================================
// Exact reference NMS per image.
// =====================================================================
#define MAXC 1024
__global__ __launch_bounds__(1024) void k_nms(
    const float* __restrict__ prob, float* __restrict__ onms, float* __restrict__ opred)
{
  __shared__ unsigned sup[MAXC * 32];
  __shared__ unsigned long long skey[MAXC];
  __shared__ unsigned syx[MAXC];
  __shared__ unsigned hist[256];
  __shared__ unsigned vword[32];
  __shared__ unsigned sh_prefix, sh_K, sh_cG, sh_pG, sh_pE;

  int n = blockIdx.x;
  int tid = threadIdx.x;
  const float* p = prob + (size_t)n * 76800;
  float* on = onms + (size_t)n * 76800;
  float* op = opred + (size_t)n * 76800;

  for (int k = tid; k < 76800; k += 1024) { on[k] = 0.f; op[k] = 0.f; }

  if (tid == 0) { sh_prefix = 0u; sh_K = MAXC; sh_cG = 0u; sh_pG = 0u; sh_pE = 0u; }

  for (int round = 0; round < 4; ++round) {
    if (tid < 256) hist[tid] = 0u;
    __syncthreads();
    unsigned prefix = sh_prefix;
    int shift = 24 - 8 * round;
    unsigned maskHi = (round == 0) ? 0u : (0xFFFFFFFFu << (shift + 8));
    for (int k = tid; k < 76800; k += 1024) {
      unsigned b = __float_as_uint(p[k]);
      if ((b & maskHi) == prefix) atomicAdd(&hist[(b >> shift) & 255], 1u);
    }
    __syncthreads();
    if (tid == 0) {
      unsigned K = sh_K, cum = 0u;
      int bin = 255;
      for (; bin >= 0; --bin) {
        unsigned cgt = hist[bin];
        if (cum + cgt >= K) break;
        cum += cgt;
      }
      sh_prefix = prefix | ((unsigned)bin << shift);
      sh_K = K - cum;
      sh_cG += cum;
    }
    __syncthreads();
  }
  unsigned T = sh_prefix;
  unsigned Kfill = sh_K;
  unsigned Cgt = sh_cG;

  unsigned* eq = sup;
  __syncthreads();
  for (int k = tid; k < 76800; k += 1024) {
    unsigned b = __float_as_uint(p[k]);
    if (b > T) {
      unsigned pos = atomicAdd(&sh_pG, 1u);
      skey[pos] = ((unsigned long long)b << 32) | (unsigned)(~(unsigned)k);
    } else if (b == T) {
      unsigned pos = atomicAdd(&sh_pE, 1u);
      if (pos < 2048u) eq[pos] = (unsigned)k;
    }
  }
  __syncthreads();
  unsigned cE = sh_pE;
  for (int k = tid; k < 2048; k += 1024)
    if ((unsigned)k >= cE) eq[k] = 0xFFFFFFFFu;
  __syncthreads();
  for (int k = 2; k <= 2048; k <<= 1) {
    for (int j = k >> 1; j > 0; j >>= 1) {
      int t = tid;
      int i = ((t & ~(j - 1)) << 1) | (t & (j - 1));
      int l = i | j;
      bool up = ((i & k) == 0);
      unsigned a = eq[i], b2 = eq[l];
      if (up ? (a > b2) : (a < b2)) { eq[i] = b2; eq[l] = a; }
      __syncthreads();
    }
  }
  for (int m2 = tid; m2 < (int)Kfill; m2 += 1024)
    skey[Cgt + m2] = ((unsigned long long)T << 32) | (unsigned)(~eq[m2]);
  __syncthreads();

  for (int k = 2; k <= MAXC; k <<= 1) {
    for (int j = k >> 1; j > 0; j >>= 1) {
      int i = tid;
      int l = i ^ j;
      if (l > i) {
        unsigned long long a = skey[i], b2 = skey[l];
        bool up = ((i & k) == 0);
        if (up ? (a < b2) : (a > b2)) { skey[i] = b2; skey[l] = a; }
      }
      __syncthreads();
    }
  }

  if (tid < 32) vword[tid] = 0u;
  __syncthreads();
  {
    unsigned long long key = skey[tid];
    unsigned vb = (unsigned)(key >> 32);
    float val = __uint_as_float(vb);
    unsigned id = ~(unsigned)key;
    unsigned y = id / 320u, xx = id - 320u * y;
    syx[tid] = (y << 16) | xx;
    if (val > DET_THRESH) atomicOr(&vword[tid >> 5], 1u << (tid & 31));
  }
  __syncthreads();

  {
    unsigned myyx = syx[tid];
    int ty = (int)(myyx >> 16), tx = (int)(myyx & 0xFFFFu);
    for (int w = 0; w < 32; ++w) {
      unsigned bits = 0u;
#pragma unroll 8
      for (int b2 = 0; b2 < 32; ++b2) {
        int j = w * 32 + b2;
        if (j > tid) {
          unsigned o = syx[j];
          int dy = ty - (int)(o >> 16); dy = dy < 0 ? -dy : dy;
          int dx = tx - (int)(o & 0xFFFFu); dx = dx < 0 ? -dx : dx;
          if (((dy | dx) < 4) && (dy + dx) <= 4) bits |= 1u << b2;
        }
      }
      sup[tid * 32 + w] = bits;
    }
  }
  __syncthreads();

  if (tid < 64) {
    int lw = tid;
    unsigned keepw = (lw < 32) ? vword[lw] : 0u;
    for (int i = 0; i < MAXC; ++i) {
      unsigned kword = __shfl(keepw, i >> 5, 64);
      if ((kword >> (i & 31)) & 1u) {
        if (lw < 32) keepw &= ~sup[i * 32 + lw];
      }
    }
    unsigned pc = (lw < 32) ? (unsigned)__builtin_popcount(keepw) : 0u;
    unsigned incl = pc;
    for (int d = 1; d < 32; d <<= 1) {
      unsigned t2 = __shfl_up(incl, d, 64);
      if (lw >= d) incl += t2;
    }
    unsigned excl = incl - pc;
    if (lw < 32) {
      int quota = 300 - (int)excl;
      if (quota <= 0) keepw = 0u;
      else if ((int)pc > quota) {
        while (__builtin_popcount(keepw) > quota)
          keepw &= ~(1u << (31 - __builtin_clz(keepw)));
      }
      unsigned kw = keepw;
      while (kw) {
        int b2 = __builtin_ffs((int)kw) - 1;
        kw &= kw - 1u;
        int i = lw * 32 + b2;
        unsigned long long key = skey[i];
        float v = __uint_as_float((unsigned)(key >> 32));
        unsigned id = ~(unsigned)key;
        on[id] = v;
        op[id] = v;
      }
    }
  }
}

// =====================================================================
extern "C" void kernel_launch(void* const* d_in, const int* in_sizes, int n_in,
                              void* d_out, int out_size, void* d_ws, size_t ws_size,
                              hipStream_t stream) {
  const float* x = (const float*)d_in[0];
  const float* w[10];
  const float* b[10];
  for (int i = 0; i < 10; ++i) {
    w[i] = (const float*)d_in[1 + 2 * i];
    b[i] = (const float*)d_in[2 + 2 * i];
  }
  float* A = (float*)d_ws;
  float* B = A + 9830400;        // 64*120*160*8
  float* prob  = (float*)d_out;
  float* onms  = prob + 614400;  // 8*240*320
  float* opred = onms + 614400;

  // Transposed weights live in the onms/opred region (dead until k_nms,
  // which rewrites it entirely). Total 921600 floats <= 1228800 available.
  float* wT1 = onms;
  float* wT2 = wT1 + 36864;
  float* wT3 = wT2 + 36864;
  float* wT4 = wT3 + 36864;
  float* wT5 = wT4 + 73728;
  float* wT6 = wT5 + 147456;
  float* wT7 = wT6 + 147456;
  float* wT8 = wT7 + 147456;

  TP tp;
  tp.src[0] = w[1]; tp.dst[0] = wT1; tp.cin[0] = 64;  tp.cout[0] = 64;
  tp.src[1] = w[2]; tp.dst[1] = wT2; tp.cin[1] = 64;  tp.cout[1] = 64;
  tp.src[2] = w[3]; tp.dst[2] = wT3; tp.cin[2] = 64;  tp.cout[2] = 64;
  tp.src[3] = w[4]; tp.dst[3] = wT4; tp.cin[3] = 64;  tp.cout[3] = 128;
  tp.src[4] = w[5]; tp.dst[4] = wT5; tp.cin[4] = 128; tp.cout[4] = 128;
  tp.src[5] = w[6]; tp.dst[5] = wT6; tp.cin[5] = 128; tp.cout[5] = 128;
  tp.src[6] = w[7]; tp.dst[6] = wT7; tp.cin[6] = 128; tp.cout[6] = 128;
  tp.src[7] = w[8]; tp.dst[7] = wT8; tp.cin[7] = 128; tp.cout[7] = 256;
  k_wT<<<dim3(1152, 8), 256, 0, stream>>>(tp);

  // conv0+conv1+pool -> A (8,64,120,160). tiles 10x30.
  k_f01<<<dim3(300, 4, 8), 256, 0, stream>>>(x, w[0], b[0], wT1, b[1], A);
  // conv2 -> B (8,64,120,160). tiles 5x15.
  k_conv<false><<<dim3(75, 4, 8), 256, 0, stream>>>(A, wT2, b[2], B, 64, 64, 120, 160, 5);
  // conv3+pool -> A (8,64,60,80)
  k_conv<true ><<<dim3(75, 4, 8), 256, 0, stream>>>(B, wT3, b[3], A, 64, 64, 120, 160, 5);
  // conv4 -> B (8,128,60,80). tiles 3x8.
  k_conv<false><<<dim3(24, 8, 8), 256, 0, stream>>>(A, wT4, b[4], B, 64, 128, 60, 80, 3);
  // conv5+pool -> A (8,128,30,40)
  k_conv<true ><<<dim3(24, 8, 8), 256, 0, stream>>>(B, wT5, b[5], A, 128, 128, 60, 80, 3);
  // conv6 -> B (8,128,30,40). tiles 2x4.
  k_conv<false><<<dim3(8, 8, 8), 256, 0, stream>>>(A, wT6, b[6], B, 128, 128, 30, 40, 2);
  // conv7 -> A
  k_conv<false><<<dim3(8, 8, 8), 256, 0, stream>>>(B, wT7, b[7], A, 128, 128, 30, 40, 2);
  // conv8 -> B (8,256,30,40)
  k_conv<false><<<dim3(8, 16, 8), 256, 0, stream>>>(A, wT8, b[8], B, 128, 256, 30, 40, 2);
  // convPb + softmax + shuffle -> prob. 10 blocks x 128 px.
  k_head<<<dim3(10, 8), 256, 0, stream>>>(B, w[9], b[9], prob);
  // NMS + top-300 -> prob_nms, pred (rewrites the wT region)
  k_nms<<<dim3(8), 1024, 0, stream>>>(prob, onms, opred);
}

// Round 10
// 2289.869 us; speedup vs baseline: 1.3256x; 1.1758x over previous
//
#include <hip/hip_runtime.h>
#include <stdint.h>

#define DET_THRESH 0.015f

// =====================================================================
// Weight pre-transpose: w[co][ci][tap] -> wT[ci*9+tap][co]  (per layer)
// =====================================================================
struct TP {
  const float* src[8];
  float* dst[8];
  int cin[8];
  int cout[8];
};

__global__ __launch_bounds__(256) void k_wT(TP tp) {
  int l = blockIdx.y;
  int n = tp.cin[l] * tp.cout[l] * 9;
  int k = blockIdx.x * 256 + threadIdx.x;
  if (k >= n) return;
  int ci9 = tp.cin[l] * 9;
  int co = k / ci9;
  int r = k - co * ci9;             // r = ci*9 + tap
  tp.dst[l][(size_t)r * tp.cout[l] + co] = tp.src[l][k];
}

// =====================================================================
// Generic 3x3 conv (+bias+relu), optional fused 2x2 maxpool.
// Tile: TW cols x TH rows x 16 co. 256 threads.
//   TW=32/TH=8: r=tid>>5, c=tid&31 (all 256 live; POOL supported).
//   TW=40/TH=6: r=tid/40, c=tid%40 (240 live; for 40/80-wide layers --
//               the 32-wide tile wasted 41% of lanes on 30x40 maps).
// Thread: 1 row x 1 col x 16 co in VGPRs (28 VGPR total fits: r7-r9
// A/B showed no AGPR traffic; kernel is genuinely VALU-bound).
// Interior tiles take a no-bounds staging fast path (uniform branch).
// =====================================================================
template <int TW, int TH, bool POOL>
__global__ __launch_bounds__(256) void k_conv(
    const float* __restrict__ in, const float* __restrict__ wT, const float* __restrict__ bias,
    float* __restrict__ out, int CIN, int COUT, int H, int W, int tilesX)
{
  constexpr int SR = TH + 2;         // staged rows
  constexpr int SC = TW + 2;         // staged cols (valid)
  constexpr int LC = TW + 4;         // LDS col stride
  constexpr int TOTAL = 4 * SR * SC;
  __shared__ float ain[4][SR][LC];

  int tile = blockIdx.x;
  int tx = tile % tilesX, ty = tile / tilesX;
  int x0 = tx * TW, y0 = ty * TH;
  int cob = blockIdx.y * 16;
  int n = blockIdx.z;

  int tid = threadIdx.x;
  int r, c;
  if (TW == 32) { r = tid >> 5; c = tid & 31; }
  else          { r = tid / TW; c = tid - r * TW; }
  bool live = (TW * TH >= 256) || (tid < TW * TH);
  int rE = live ? r : 0;

  bool full = (y0 >= 1) && (y0 + TH + 1 <= H) && (x0 >= 1) && (x0 + TW + 1 <= W);
  size_t imgBase = (size_t)n * CIN * H * W;

  float acc[16];
#pragma unroll
  for (int j = 0; j < 16; j++) acc[j] = 0.f;

  int nch = CIN >> 2;
  for (int cc = 0; cc < nch; ++cc) {
    __syncthreads();
    if (full) {
      const float* src = in + imgBase + (size_t)(cc * 4) * H * W + (y0 - 1) * W + (x0 - 1);
      for (int m = tid; m < TOTAL; m += 256) {
        int ci = m / (SR * SC);
        int rem = m - ci * (SR * SC);
        int rr = rem / SC;
        int col = rem - rr * SC;
        ain[ci][rr][col] = src[(size_t)ci * H * W + rr * W + col];
      }
    } else {
      for (int m = tid; m < TOTAL; m += 256) {
        int ci = m / (SR * SC);
        int rem = m - ci * (SR * SC);
        int rr = rem / SC;
        int col = rem - rr * SC;
        int gy = y0 - 1 + rr, gx = x0 - 1 + col;
        float v = 0.f;
        if (gy >= 0 && gy < H && gx >= 0 && gx < W)
          v = in[imgBase + ((size_t)(cc * 4 + ci) * H + gy) * W + gx];
        ain[ci][rr][col] = v;
      }
    }
    __syncthreads();
#pragma unroll
    for (int ci = 0; ci < 4; ++ci) {
      float win[3][3];
#pragma unroll
      for (int dy = 0; dy < 3; dy++) {
        win[dy][0] = ain[ci][rE + dy][c];
        win[dy][1] = ain[ci][rE + dy][c + 1];
        win[dy][2] = ain[ci][rE + dy][c + 2];
      }
      const float* wp = wT + (size_t)((cc * 4 + ci) * 9) * COUT + cob;
#pragma unroll
      for (int tap = 0; tap < 9; tap++) {
        float4 q0 = *(const float4*)(wp + tap * COUT);
        float4 q1 = *(const float4*)(wp + tap * COUT + 4);
        float4 q2 = *(const float4*)(wp + tap * COUT + 8);
        float4 q3 = *(const float4*)(wp + tap * COUT + 12);
        float a = win[tap / 3][tap % 3];
        acc[0]  = fmaf(a, q0.x, acc[0]);
        acc[1]  = fmaf(a, q0.y, acc[1]);
        acc[2]  = fmaf(a, q0.z, acc[2]);
        acc[3]  = fmaf(a, q0.w, acc[3]);
        acc[4]  = fmaf(a, q1.x, acc[4]);
        acc[5]  = fmaf(a, q1.y, acc[5]);
        acc[6]  = fmaf(a, q1.z, acc[6]);
        acc[7]  = fmaf(a, q1.w, acc[7]);
        acc[8]  = fmaf(a, q2.x, acc[8]);
        acc[9]  = fmaf(a, q2.y, acc[9]);
        acc[10] = fmaf(a, q2.z, acc[10]);
        acc[11] = fmaf(a, q2.w, acc[11]);
        acc[12] = fmaf(a, q3.x, acc[12]);
        acc[13] = fmaf(a, q3.y, acc[13]);
        acc[14] = fmaf(a, q3.z, acc[14]);
        acc[15] = fmaf(a, q3.w, acc[15]);
      }
    }
  }

  float bvv[16];
  {
    const float4* bp = (const float4*)(bias + cob);
    *(float4*)&bvv[0] = bp[0]; *(float4*)&bvv[4] = bp[1];
    *(float4*)&bvv[8] = bp[2]; *(float4*)&bvv[12] = bp[3];
  }
  int x = x0 + c;
  int y = y0 + r;
  if (!POOL) {
    if (live && y < H && x < W) {
#pragma unroll
      for (int j = 0; j < 16; j++)
        out[(((size_t)n * COUT + cob + j) * H + y) * W + x] = fmaxf(acc[j] + bvv[j], 0.f);
    }
  } else {
    // only instantiated with TW=32 (shfl pairing relies on that map)
    int Hp = H >> 1, Wp = W >> 1;
    int py = y >> 1, pxp = x >> 1;
    bool ok = ((r & 1) == 0) && ((c & 1) == 0) && (py < Hp) && (pxp < Wp);
#pragma unroll
    for (int j = 0; j < 16; j++) {
      float h = fmaxf(acc[j] + bvv[j], 0.f);
      float hc = fmaxf(h, __shfl_xor(h, 1, 64));    // col pair
      float hv = fmaxf(hc, __shfl_xor(hc, 32, 64)); // row pair
      if (ok)
        out[(((size_t)n * COUT + cob + j) * Hp + py) * Wp + pxp] = hv;
    }
  }
}

// =====================================================================
// Fused conv0(1->64)+relu -> conv1(64->64)+relu -> 2x2 maxpool.
// 32x8 tile geometry; conv0 recomputed per 4-channel chunk into LDS,
// with a no-bounds fast path for interior tiles.
// =====================================================================
__global__ __launch_bounds__(256) void k_f01(
    const float* __restrict__ x, const float* __restrict__ w0g, const float* __restrict__ b0g,
    const float* __restrict__ wT1, const float* __restrict__ b1g, float* __restrict__ out)
{
  const int H = 240, W = 320;
  __shared__ float in_raw[12][36];
  __shared__ float a0[4][10][36];
  __shared__ float w0l[576];
  __shared__ float b0l[64];

  int tile = blockIdx.x;              // tilesX=10, tilesY=30
  int tx = tile % 10, ty = tile / 10;
  int x0 = tx * 32, y0 = ty * 8;
  int cob = blockIdx.y * 16;          // 0..3
  int n = blockIdx.z;

  int tid = threadIdx.x;
  int r = tid >> 5;
  int c = tid & 31;

  bool fullT = (y0 >= 1) && (y0 + 9 <= H) && (x0 >= 1) && (x0 + 33 <= W);

  for (int k = tid; k < 576; k += 256) w0l[k] = w0g[k];
  if (tid < 64) b0l[tid] = b0g[tid];
  for (int m = tid; m < 432; m += 256) {
    int rr = m / 36, col = m - rr * 36;
    int gy = y0 - 2 + rr, gx = x0 - 2 + col;
    in_raw[rr][col] = (gy >= 0 && gy < H && gx >= 0 && gx < W)
                          ? x[(size_t)n * (H * W) + gy * W + gx] : 0.f;
  }

  float acc[16];
#pragma unroll
  for (int j = 0; j < 16; j++) acc[j] = 0.f;

  for (int cc = 0; cc < 16; ++cc) {
    __syncthreads();                  // in_raw/w0l ready; a0 free
    // conv0 chunk -> a0 (zero OUTSIDE image: conv1 'SAME' zero-padding)
    if (fullT) {
      for (int m = tid; m < 1360; m += 256) {
        int ch = m / 340;
        int rem = m - ch * 340;
        int rr = rem / 34;
        int col = rem - rr * 34;
        const float* wp = &w0l[(cc * 4 + ch) * 9];
        float s = b0l[cc * 4 + ch];
#pragma unroll
        for (int dy = 0; dy < 3; dy++)
#pragma unroll
          for (int dx = 0; dx < 3; dx++)
            s = fmaf(in_raw[rr + dy][col + dx], wp[dy * 3 + dx], s);
        a0[ch][rr][col] = fmaxf(s, 0.f);
      }
    } else {
      for (int m = tid; m < 1360; m += 256) {
        int ch = m / 340;
        int rem = m - ch * 340;
        int rr = rem / 34;
        int col = rem - rr * 34;
        int gy = y0 - 1 + rr, gx = x0 - 1 + col;
        float v = 0.f;
        if (gy >= 0 && gy < H && gx >= 0 && gx < W) {
          const float* wp = &w0l[(cc * 4 + ch) * 9];
          float s = b0l[cc * 4 + ch];
#pragma unroll
          for (int dy = 0; dy < 3; dy++)
#pragma unroll
            for (int dx = 0; dx < 3; dx++)
              s = fmaf(in_raw[rr + dy][col + dx], wp[dy * 3 + dx], s);
          v = fmaxf(s, 0.f);
        }
        a0[ch][rr][col] = v;
      }
    }
    __syncthreads();
#pragma unroll
    for (int ci = 0; ci < 4; ++ci) {
      float win[3][3];
#pragma unroll
      for (int dy = 0; dy < 3; dy++) {
        win[dy][0] = a0[ci][r + dy][c];
        win[dy][1] = a0[ci][r + dy][c + 1];
        win[dy][2] = a0[ci][r + dy][c + 2];
      }
      const float* wp = wT1 + (size_t)((cc * 4 + ci) * 9) * 64 + cob;
#pragma unroll
      for (int tap = 0; tap < 9; tap++) {
        float4 q0 = *(const float4*)(wp + tap * 64);
        float4 q1 = *(const float4*)(wp + tap * 64 + 4);
        float4 q2 = *(const float4*)(wp + tap * 64 + 8);
        float4 q3 = *(const float4*)(wp + tap * 64 + 12);
        float a = win[tap / 3][tap % 3];
        acc[0]  = fmaf(a, q0.x, acc[0]);
        acc[1]  = fmaf(a, q0.y, acc[1]);
        acc[2]  = fmaf(a, q0.z, acc[2]);
        acc[3]  = fmaf(a, q0.w, acc[3]);
        acc[4]  = fmaf(a, q1.x, acc[4]);
        acc[5]  = fmaf(a, q1.y, acc[5]);
        acc[6]  = fmaf(a, q1.z, acc[6]);
        acc[7]  = fmaf(a, q1.w, acc[7]);
        acc[8]  = fmaf(a, q2.x, acc[8]);
        acc[9]  = fmaf(a, q2.y, acc[9]);
        acc[10] = fmaf(a, q2.z, acc[10]);
        acc[11] = fmaf(a, q2.w, acc[11]);
        acc[12] = fmaf(a, q3.x, acc[12]);
        acc[13] = fmaf(a, q3.y, acc[13]);
        acc[14] = fmaf(a, q3.z, acc[14]);
        acc[15] = fmaf(a, q3.w, acc[15]);
      }
    }
  }

  // bias + relu + 2x2 maxpool + store (out: 8,64,120,160)
  float bvv[16];
  {
    const float4* bp = (const float4*)(b1g + cob);
    *(float4*)&bvv[0] = bp[0]; *(float4*)&bvv[4] = bp[1];
    *(float4*)&bvv[8] = bp[2]; *(float4*)&bvv[12] = bp[3];
  }
  int Hp = 120, Wp = 160;
  int py = (y0 + r) >> 1, pxp = (x0 + c) >> 1;
  bool ok = ((r & 1) == 0) && ((c & 1) == 0);
#pragma unroll
  for (int j = 0; j < 16; j++) {
    float h = fmaxf(acc[j] + bvv[j], 0.f);
    float hc = fmaxf(h, __shfl_xor(h, 1, 64));
    float hv = fmaxf(hc, __shfl_xor(hc, 32, 64));
    if (ok)
      out[(((size_t)n * 64 + cob + j) * Hp + py) * Wp + pxp] = hv;
  }
}

// =====================================================================
// Head: conv9 (1x1, 256->65) + bias + softmax(65) + drop dustbin + shuffle
// 2-lane teams: even lane co 0..33, odd lane co 34..64.
// =====================================================================
__global__ __launch_bounds__(256) void k_head(
    const float* __restrict__ act, const float* __restrict__ w9, const float* __restrict__ b9,
    float* __restrict__ prob)
{
  __shared__ float wl[256 * 68];
  int n = blockIdx.y;
  int tid = threadIdx.x;
  for (int k = tid; k < 65 * 256; k += 256) {
    int co = k / 256, ci = k % 256;
    wl[ci * 68 + co] = w9[k];
  }
  for (int ci = tid; ci < 256; ci += 256) {
    wl[ci * 68 + 65] = 0.f; wl[ci * 68 + 66] = 0.f; wl[ci * 68 + 67] = 0.f;
  }
  __syncthreads();
  int px = blockIdx.x * 128 + (tid >> 1);
  int half = tid & 1;
  bool live = (px < 1200);
  int cbase = half * 34;
  int nreal = half ? 31 : 34;    // real co count (incl. dustbin 64 on odd)

  float accv[34];
#pragma unroll
  for (int i = 0; i < 34; i++) accv[i] = 0.f;

  if (live) {
    for (int ci = 0; ci < 256; ++ci) {
      float a = act[((size_t)n * 256 + ci) * 1200 + px];
      const float2* wp = (const float2*)&wl[ci * 68 + cbase];
#pragma unroll
      for (int g = 0; g < 17; g++) {
        float2 wv = wp[g];
        accv[g * 2 + 0] = fmaf(a, wv.x, accv[g * 2 + 0]);
        accv[g * 2 + 1] = fmaf(a, wv.y, accv[g * 2 + 1]);
      }
    }
  }
  // bias + softmax across the lane pair
  for (int i = 0; i < 34; i++)
    if (i < nreal) accv[i] += b9[cbase + i];
  float m = -1e30f;
  for (int i = 0; i < 34; i++)
    if (i < nreal) m = fmaxf(m, accv[i]);
  m = fmaxf(m, __shfl_xor(m, 1, 64));
  float s = 0.f;
  for (int i = 0; i < 34; i++)
    if (i < nreal) { accv[i] = __expf(accv[i] - m); s += accv[i]; }
  s += __shfl_xor(s, 1, 64);
  float inv = 1.f / s;

  if (live) {
    int hc = px / 40, wc = px % 40;
    float* pb = prob + (size_t)n * 76800;
    int nw = half ? 30 : 34;     // write only co < 64
    for (int i = 0; i < nw; i++) {
      int co = cbase + i;
      pb[(hc * 8 + (co >> 3)) * 320 + wc * 8 + (co & 7)] = accv[i] * inv;
    }
  }
}

// =====================================================================
// Exact reference NMS per image.
// =====================================================================
#define MAXC 1024
__global__ __launch_bounds__(1024) void k_nms(
    const float* __restrict__ prob, float* __restrict__ onms, float* __restrict__ opred)
{
  __shared__ unsigned sup[MAXC * 32];
  __shared__ unsigned long long skey[MAXC];
  __shared__ unsigned syx[MAXC];
  __shared__ unsigned hist[256];
  __shared__ unsigned vword[32];
  __shared__ unsigned sh_prefix, sh_K, sh_cG, sh_pG, sh_pE;

  int n = blockIdx.x;
  int tid = threadIdx.x;
  const float* p = prob + (size_t)n * 76800;
  float* on = onms + (size_t)n * 76800;
  float* op = opred + (size_t)n * 76800;

  for (int k = tid; k < 76800; k += 1024) { on[k] = 0.f; op[k] = 0.f; }

  if (tid == 0) { sh_prefix = 0u; sh_K = MAXC; sh_cG = 0u; sh_pG = 0u; sh_pE = 0u; }

  for (int round = 0; round < 4; ++round) {
    if (tid < 256) hist[tid] = 0u;
    __syncthreads();
    unsigned prefix = sh_prefix;
    int shift = 24 - 8 * round;
    unsigned maskHi = (round == 0) ? 0u : (0xFFFFFFFFu << (shift + 8));
    for (int k = tid; k < 76800; k += 1024) {
      unsigned b = __float_as_uint(p[k]);
      if ((b & maskHi) == prefix) atomicAdd(&hist[(b >> shift) & 255], 1u);
    }
    __syncthreads();
    if (tid == 0) {
      unsigned K = sh_K, cum = 0u;
      int bin = 255;
      for (; bin >= 0; --bin) {
        unsigned cgt = hist[bin];
        if (cum + cgt >= K) break;
        cum += cgt;
      }
      sh_prefix = prefix | ((unsigned)bin << shift);
      sh_K = K - cum;
      sh_cG += cum;
    }
    __syncthreads();
  }
  unsigned T = sh_prefix;
  unsigned Kfill = sh_K;
  unsigned Cgt = sh_cG;

  unsigned* eq = sup;
  __syncthreads();
  for (int k = tid; k < 76800; k += 1024) {
    unsigned b = __float_as_uint(p[k]);
    if (b > T) {
      unsigned pos = atomicAdd(&sh_pG, 1u);
      skey[pos] = ((unsigned long long)b << 32) | (unsigned)(~(unsigned)k);
    } else if (b == T) {
      unsigned pos = atomicAdd(&sh_pE, 1u);
      if (pos < 2048u) eq[pos] = (unsigned)k;
    }
  }
  __syncthreads();
  unsigned cE = sh_pE;
  for (int k = tid; k < 2048; k += 1024)
    if ((unsigned)k >= cE) eq[k] = 0xFFFFFFFFu;
  __syncthreads();
  for (int k = 2; k <= 2048; k <<= 1) {
    for (int j = k >> 1; j > 0; j >>= 1) {
      int t = tid;
      int i = ((t & ~(j - 1)) << 1) | (t & (j - 1));
      int l = i | j;
      bool up = ((i & k) == 0);
      unsigned a = eq[i], b2 = eq[l];
      if (up ? (a > b2) : (a < b2)) { eq[i] = b2; eq[l] = a; }
      __syncthreads();
    }
  }
  for (int m2 = tid; m2 < (int)Kfill; m2 += 1024)
    skey[Cgt + m2] = ((unsigned long long)T << 32) | (unsigned)(~eq[m2]);
  __syncthreads();

  for (int k = 2; k <= MAXC; k <<= 1) {
    for (int j = k >> 1; j > 0; j >>= 1) {
      int i = tid;
      int l = i ^ j;
      if (l > i) {
        unsigned long long a = skey[i], b2 = skey[l];
        bool up = ((i & k) == 0);
        if (up ? (a < b2) : (a > b2)) { skey[i] = b2; skey[l] = a; }
      }
      __syncthreads();
    }
  }

  if (tid < 32) vword[tid] = 0u;
  __syncthreads();
  {
    unsigned long long key = skey[tid];
    unsigned vb = (unsigned)(key >> 32);
    float val = __uint_as_float(vb);
    unsigned id = ~(unsigned)key;
    unsigned y = id / 320u, xx = id - 320u * y;
    syx[tid] = (y << 16) | xx;
    if (val > DET_THRESH) atomicOr(&vword[tid >> 5], 1u << (tid & 31));
  }
  __syncthreads();

  {
    unsigned myyx = syx[tid];
    int ty = (int)(myyx >> 16), tx = (int)(myyx & 0xFFFFu);
    for (int w = 0; w < 32; ++w) {
      unsigned bits = 0u;
#pragma unroll 8
      for (int b2 = 0; b2 < 32; ++b2) {
        int j = w * 32 + b2;
        if (j > tid) {
          unsigned o = syx[j];
          int dy = ty - (int)(o >> 16); dy = dy < 0 ? -dy : dy;
          int dx = tx - (int)(o & 0xFFFFu); dx = dx < 0 ? -dx : dx;
          if (((dy | dx) < 4) && (dy + dx) <= 4) bits |= 1u << b2;
        }
      }
      sup[tid * 32 + w] = bits;
    }
  }
  __syncthreads();

  if (tid < 64) {
    int lw = tid;
    unsigned keepw = (lw < 32) ? vword[lw] : 0u;
    for (int i = 0; i < MAXC; ++i) {
      unsigned kword = __shfl(keepw, i >> 5, 64);
      if ((kword >> (i & 31)) & 1u) {
        if (lw < 32) keepw &= ~sup[i * 32 + lw];
      }
    }
    unsigned pc = (lw < 32) ? (unsigned)__builtin_popcount(keepw) : 0u;
    unsigned incl = pc;
    for (int d = 1; d < 32; d <<= 1) {
      unsigned t2 = __shfl_up(incl, d, 64);
      if (lw >= d) incl += t2;
    }
    unsigned excl = incl - pc;
    if (lw < 32) {
      int quota = 300 - (int)excl;
      if (quota <= 0) keepw = 0u;
      else if ((int)pc > quota) {
        while (__builtin_popcount(keepw) > quota)
          keepw &= ~(1u << (31 - __builtin_clz(keepw)));
      }
      unsigned kw = keepw;
      while (kw) {
        int b2 = __builtin_ffs((int)kw) - 1;
        kw &= kw - 1u;
        int i = lw * 32 + b2;
        unsigned long long key = skey[i];
        float v = __uint_as_float((unsigned)(key >> 32));
        unsigned id = ~(unsigned)key;
        on[id] = v;
        op[id] = v;
      }
    }
  }
}

// =====================================================================
extern "C" void kernel_launch(void* const* d_in, const int* in_sizes, int n_in,
                              void* d_out, int out_size, void* d_ws, size_t ws_size,
                              hipStream_t stream) {
  const float* x = (const float*)d_in[0];
  const float* w[10];
  const float* b[10];
  for (int i = 0; i < 10; ++i) {
    w[i] = (const float*)d_in[1 + 2 * i];
    b[i] = (const float*)d_in[2 + 2 * i];
  }
  float* A = (float*)d_ws;
  float* B = A + 9830400;        // 64*120*160*8
  float* prob  = (float*)d_out;
  float* onms  = prob + 614400;  // 8*240*320
  float* opred = onms + 614400;

  // Transposed weights live in the onms/opred region (dead until k_nms,
  // which rewrites it entirely). Total 921600 floats <= 1228800 available.
  float* wT1 = onms;
  float* wT2 = wT1 + 36864;
  float* wT3 = wT2 + 36864;
  float* wT4 = wT3 + 36864;
  float* wT5 = wT4 + 73728;
  float* wT6 = wT5 + 147456;
  float* wT7 = wT6 + 147456;
  float* wT8 = wT7 + 147456;

  TP tp;
  tp.src[0] = w[1]; tp.dst[0] = wT1; tp.cin[0] = 64;  tp.cout[0] = 64;
  tp.src[1] = w[2]; tp.dst[1] = wT2; tp.cin[1] = 64;  tp.cout[1] = 64;
  tp.src[2] = w[3]; tp.dst[2] = wT3; tp.cin[2] = 64;  tp.cout[2] = 64;
  tp.src[3] = w[4]; tp.dst[3] = wT4; tp.cin[3] = 64;  tp.cout[3] = 128;
  tp.src[4] = w[5]; tp.dst[4] = wT5; tp.cin[4] = 128; tp.cout[4] = 128;
  tp.src[5] = w[6]; tp.dst[5] = wT6; tp.cin[5] = 128; tp.cout[5] = 128;
  tp.src[6] = w[7]; tp.dst[6] = wT7; tp.cin[6] = 128; tp.cout[6] = 128;
  tp.src[7] = w[8]; tp.dst[7] = wT8; tp.cin[7] = 128; tp.cout[7] = 256;
  k_wT<<<dim3(1152, 8), 256, 0, stream>>>(tp);

  // conv0+conv1+pool -> A (8,64,120,160). tiles 10x30.
  k_f01<<<dim3(300, 4, 8), 256, 0, stream>>>(x, w[0], b[0], wT1, b[1], A);
  // conv2 -> B (8,64,120,160). 32x8 tiles, 5x15.
  k_conv<32, 8, false><<<dim3(75, 4, 8), 256, 0, stream>>>(A, wT2, b[2], B, 64, 64, 120, 160, 5);
  // conv3+pool -> A (8,64,60,80)
  k_conv<32, 8, true ><<<dim3(75, 4, 8), 256, 0, stream>>>(B, wT3, b[3], A, 64, 64, 120, 160, 5);
  // conv4 -> B (8,128,60,80). 40x6 tiles, 2x10.
  k_conv<40, 6, false><<<dim3(20, 8, 8), 256, 0, stream>>>(A, wT4, b[4], B, 64, 128, 60, 80, 2);
  // conv5+pool -> A (8,128,30,40). 32x8 tiles, 3x8.
  k_conv<32, 8, true ><<<dim3(24, 8, 8), 256, 0, stream>>>(B, wT5, b[5], A, 128, 128, 60, 80, 3);
  // conv6 -> B (8,128,30,40). 40x6 tiles, 1x5.
  k_conv<40, 6, false><<<dim3(5, 8, 8), 256, 0, stream>>>(A, wT6, b[6], B, 128, 128, 30, 40, 1);
  // conv7 -> A
  k_conv<40, 6, false><<<dim3(5, 8, 8), 256, 0, stream>>>(B, wT7, b[7], A, 128, 128, 30, 40, 1);
  // conv8 -> B (8,256,30,40)
  k_conv<40, 6, false><<<dim3(5, 16, 8), 256, 0, stream>>>(A, wT8, b[8], B, 128, 256, 30, 40, 1);
  // convPb + softmax + shuffle -> prob. 10 blocks x 128 px.
  k_head<<<dim3(10, 8), 256, 0, stream>>>(B, w[9], b[9], prob);
  // NMS + top-300 -> prob_nms, pred (rewrites the wT region)
  k_nms<<<dim3(8), 1024, 0, stream>>>(prob, onms, opred);
}